// Round 10
// baseline (251.980 us; speedup 1.0000x reference)
//
#include <hip/hip_runtime.h>
#include <hip/hip_bf16.h>
#include <stdint.h>

// Problem constants
// B=128 STREAM=512 IN_CH=4 EXTRA=5 GROUPS=2 DEPTH=3 STEP=16 LENGTH=32 RNN=256 OUT=10
// C=10 SIG_C=1110 W=31 F=2220, padded K = 2240, GEMM M = 31*128 = 3968, N = 768
// gi layout (f16): per (t, bb, tid) 24 contiguous f16:
//   off = ((t*8+bb)*512 + tid)*24 + (gs*2+tc)*4 + rr
// GRU: r,z gates fp8 e4m3 (W_hh*16) pinned a[0:63]; n gate f16 pinned a[64:127];
// acc a[128:151]. K-loop = one asm block, 6-deep ds_read pipeline (lgkmcnt(5)).
// GEMM: 3-buffer LDS pipeline, prefetch 2 tiles ahead, s_waitcnt vmcnt(4)+s_barrier
// (loads stay in flight across the barrier -- kills the m97 barrier-drain stall).

typedef _Float16 f16;
typedef f16  f16x4 __attribute__((ext_vector_type(4)));
typedef f16  f16x8 __attribute__((ext_vector_type(8)));
typedef float f32x2 __attribute__((ext_vector_type(2)));
typedef float f32x4 __attribute__((ext_vector_type(4)));

#define ASYNC16(gp, lp) __builtin_amdgcn_global_load_lds( \
    (const __attribute__((address_space(1))) void*)(gp),  \
    (__attribute__((address_space(3))) void*)(lp), 16, 0, 0)

#define BAR_LDS() do { asm volatile("s_waitcnt lgkmcnt(0)" ::: "memory"); \
                       __builtin_amdgcn_s_barrier();                      \
                       asm volatile("" ::: "memory"); } while (0)

// ---------------------------------------------------------------- K0: prep
// blocks [0,840):    W_ih f32 -> f16 (pad 2220->2240), 8 elems/thread
// blocks [840,936):  W_hh f32 -> f16 (all) + fp8*16 (r,z rows), 8 elems/thread
// blocks [936,2920): signature chains, 4 per block
__global__ __launch_bounds__(256) void prep_kernel(const float* __restrict__ x,
                                                   const float* __restrict__ W_aug,
                                                   const float* __restrict__ Wih,
                                                   const float* __restrict__ Whh,
                                                   f16* __restrict__ sig16,
                                                   f16* __restrict__ wih16,
                                                   f16* __restrict__ whh16,
                                                   uint8_t* __restrict__ whh8) {
    __shared__ float dxs[4][31][10];
    const int tid = threadIdx.x;
    if (blockIdx.x < 840) {
        int c = blockIdx.x * 256 + tid;          // chunk 0..215039
        int r = c / 280, kc = (c - r * 280) * 8;
        const float* src = Wih + (size_t)r * 2220 + kc;
        f16x8 o;
        if (kc + 8 <= 2220) {
            float4 v0 = *(const float4*)(src);
            float4 v1 = *(const float4*)(src + 4);
            o[0]=(f16)v0.x; o[1]=(f16)v0.y; o[2]=(f16)v0.z; o[3]=(f16)v0.w;
            o[4]=(f16)v1.x; o[5]=(f16)v1.y; o[6]=(f16)v1.z; o[7]=(f16)v1.w;
        } else {
#pragma unroll
            for (int j = 0; j < 8; j++)
                o[j] = (f16)((kc + j < 2220) ? src[j] : 0.0f);
        }
        *(f16x8*)(wih16 + (size_t)r * 2240 + kc) = o;
        return;
    }
    if (blockIdx.x < 936) {
        int c2 = ((int)blockIdx.x - 840) * 256 + tid;    // 0..24575
        int j8 = c2 * 8;
        float w[8];
        {
            float4 v0 = *(const float4*)(Whh + j8);
            float4 v1 = *(const float4*)(Whh + j8 + 4);
            w[0]=v0.x; w[1]=v0.y; w[2]=v0.z; w[3]=v0.w;
            w[4]=v1.x; w[5]=v1.y; w[6]=v1.z; w[7]=v1.w;
        }
        f16x8 o;
#pragma unroll
        for (int j = 0; j < 8; j++) o[j] = (f16)w[j];
        *(f16x8*)(whh16 + j8) = o;
        if (j8 < 131072) {                       // r,z gate rows -> fp8 e4m3 (x16)
            uint32_t p01 = (uint32_t)__builtin_amdgcn_cvt_pk_fp8_f32(w[0]*16.f, w[1]*16.f, 0, false) & 0xffffu;
            uint32_t p23 = (uint32_t)__builtin_amdgcn_cvt_pk_fp8_f32(w[2]*16.f, w[3]*16.f, 0, false) & 0xffffu;
            uint32_t p45 = (uint32_t)__builtin_amdgcn_cvt_pk_fp8_f32(w[4]*16.f, w[5]*16.f, 0, false) & 0xffffu;
            uint32_t p67 = (uint32_t)__builtin_amdgcn_cvt_pk_fp8_f32(w[6]*16.f, w[7]*16.f, 0, false) & 0xffffu;
            uint2 st = make_uint2(p01 | (p23 << 16), p45 | (p67 << 16));
            *(uint2*)(whh8 + j8) = st;
        }
        return;
    }
    // ---- signature chains (block-uniform branch; __syncthreads safe)
    const int sub = tid >> 6, t64 = tid & 63;
    const int cid = ((int)blockIdx.x - 936) * 4 + sub;   // 0..7935
    const int w = cid % 31;
    const int bg = cid / 31;
    const int b = bg >> 1, g = bg & 1;
    if (t64 < 31) {
        int s = w * 16 + t64;
        const float4 x0 = *(const float4*)(x + ((size_t)b * 512 + s) * 4);
        const float4 x1 = *(const float4*)(x + ((size_t)b * 512 + s + 1) * 4);
        float d0 = x1.x - x0.x, d1 = x1.y - x0.y, d2 = x1.z - x0.z, d3 = x1.w - x0.w;
        dxs[sub][t64][0] = d0; dxs[sub][t64][1] = d1;
        dxs[sub][t64][2] = d2; dxs[sub][t64][3] = d3;
        dxs[sub][t64][4] = 1.0f / 511.0f;
#pragma unroll
        for (int e = 0; e < 5; e++) {
            const float* wa = W_aug + (g * 5 + e) * 4;
            dxs[sub][t64][5 + e] = d0 * wa[0] + d1 * wa[1] + d2 * wa[2] + d3 * wa[3];
        }
    }
    __syncthreads();
    size_t base = ((size_t)(w * 128 + b)) * 2240 + (size_t)g * 1110;
    if (t64 < 50) {
        int p0 = 2 * t64, p1 = p0 + 1;
        int i0 = p0 / 10, j0 = p0 % 10, j1 = j0 + 1;
        float s3a[10], s3b[10];
#pragma unroll
        for (int k = 0; k < 10; k++) { s3a[k] = 0.f; s3b[k] = 0.f; }
        float s2a = 0.f, s2b = 0.f, s1 = 0.f;
        for (int l = 0; l < 31; l++) {
            float dx[10];
#pragma unroll
            for (int c = 0; c < 10; c++) dx[c] = dxs[sub][l][c];
            float t0 = s1 + dx[i0] * (1.0f / 3.0f);
            float a0 = s2a + t0 * (0.5f * dx[j0]);
            float a1 = s2b + t0 * (0.5f * dx[j1]);
#pragma unroll
            for (int k = 0; k < 10; k++) { s3a[k] += a0 * dx[k]; s3b[k] += a1 * dx[k]; }
            float u = s1 + 0.5f * dx[i0];
            s2a += u * dx[j0];
            s2b += u * dx[j1];
            s1 += dx[i0];
        }
        sig16[base + 10 + p0] = (f16)s2a;
        sig16[base + 10 + p1] = (f16)s2b;
#pragma unroll
        for (int k = 0; k < 10; k++) {
            sig16[base + 110 + p0 * 10 + k] = (f16)s3a[k];
            sig16[base + 110 + p1 * 10 + k] = (f16)s3b[k];
        }
    } else if (t64 < 60) {
        int c = t64 - 50;
        float s = 0.f;
        for (int l = 0; l < 31; l++) s += dxs[sub][l][c];
        sig16[base + c] = (f16)s;
    }
    if (g == 1 && t64 < 20)
        sig16[((size_t)(w * 128 + b)) * 2240 + 2220 + t64] = (f16)0.0f;
}

// ---------------------------------------------------------------- K2: gi = sig @ W_ih.T + biases (f16, GRU lane order)
// 3-buffer pipelined K-loop: prefetch depth 2, loads in flight across the barrier.
__global__ __launch_bounds__(256) void gemm_kernel(const f16* __restrict__ A,     // 3968 x 2240
                                                   const f16* __restrict__ Bw,    // 768 x 2240 f16
                                                   const float* __restrict__ bias,
                                                   const float* __restrict__ bhh,
                                                   f16* __restrict__ Cgi) {
    __shared__ __align__(16) f16 As[3][128 * 32];
    __shared__ __align__(16) f16 Bs[3][128 * 32];
    const int tid = threadIdx.x, lane = tid & 63, wid = tid >> 6;
    const int wm = wid >> 1, wn = wid & 1;
    const int Mbase = blockIdx.y * 128, Nbase = blockIdx.x * 128;
    const int lr = lane >> 2, lk = lane & 3;
    const int l16 = lane & 15, quad = lane >> 4;
    const int r0a = wid * 32, r0b = wid * 32 + 16;
    const f16* gaA0 = A  + (size_t)(Mbase + r0a + lr) * 2240 + lk * 8;
    const f16* gaA1 = A  + (size_t)(Mbase + r0b + lr) * 2240 + lk * 8;
    const f16* gbB0 = Bw + (size_t)(Nbase + r0a + lr) * 2240 + lk * 8;
    const f16* gbB1 = Bw + (size_t)(Nbase + r0b + lr) * 2240 + lk * 8;

#define GISSUE(KT, BUF) do { \
        int _k0 = (KT) * 32; \
        ASYNC16(gaA0 + _k0, &As[BUF][r0a * 32]); \
        ASYNC16(gbB0 + _k0, &Bs[BUF][r0a * 32]); \
        ASYNC16(gaA1 + _k0, &As[BUF][r0b * 32]); \
        ASYNC16(gbB1 + _k0, &Bs[BUF][r0b * 32]); } while (0)

#define GCOMPUTE(BUF) do { \
        f16x8 af[4], bf[4]; \
        _Pragma("unroll") \
        for (int mt = 0; mt < 4; mt++) \
            af[mt] = *(const f16x8*)&As[BUF][(wm * 64 + mt * 16 + l16) * 32 + quad * 8]; \
        _Pragma("unroll") \
        for (int nt = 0; nt < 4; nt++) \
            bf[nt] = *(const f16x8*)&Bs[BUF][(wn * 64 + nt * 16 + l16) * 32 + quad * 8]; \
        _Pragma("unroll") \
        for (int mt = 0; mt < 4; mt++) \
            _Pragma("unroll") \
            for (int nt = 0; nt < 4; nt++) \
                acc[mt][nt] = __builtin_amdgcn_mfma_f32_16x16x32_f16(af[mt], bf[nt], acc[mt][nt], 0, 0, 0); } while (0)

    f32x4 acc[4][4];
#pragma unroll
    for (int mt = 0; mt < 4; mt++)
#pragma unroll
        for (int nt = 0; nt < 4; nt++) acc[mt][nt] = (f32x4){0.f, 0.f, 0.f, 0.f};

    GISSUE(0, 0);
    GISSUE(1, 1);
    for (int kt = 0; kt < 69; kt++) {
        // wait only the oldest 4 loads (tile kt); tile kt+1's 4 stay in flight
        asm volatile("s_waitcnt vmcnt(4) lgkmcnt(0)\n\ts_barrier" ::: "memory");
        if (kt < 68) GISSUE(kt + 2, (kt + 2) % 3);
        GCOMPUTE(kt % 3);
    }
    asm volatile("s_waitcnt vmcnt(0) lgkmcnt(0)\n\ts_barrier" ::: "memory");
    GCOMPUTE(0);   // tile 69 -> buffer 69%3 == 0

    const int t = blockIdx.y;
#pragma unroll
    for (int mt = 0; mt < 4; mt++) {
        const int bbv = wm * 4 + mt;
#pragma unroll
        for (int nt = 0; nt < 4; nt++) {
            int col = Nbase + wn * 64 + nt * 16 + l16;
            float bvv = bias[col] + (col < 512 ? bhh[col] : 0.0f);   // fold b_hh into r,z
            int gs = col >> 8, hcc = col & 255;
            int gw = hcc >> 5, gtc = (hcc >> 4) & 1, gl = hcc & 15;
            int gtid = gw * 64 + quad * 16 + gl;
            size_t off = ((size_t)(t * 8 + bbv) * 512 + gtid) * 24 + (gs * 2 + gtc) * 4;
            f16x4 st;
#pragma unroll
            for (int rr = 0; rr < 4; rr++) st[rr] = (f16)(acc[mt][nt][rr] + bvv);
            *(f16x4*)(Cgi + off) = st;
        }
    }
#undef GISSUE
#undef GCOMPUTE
}

// ---------------------------------------------------------------- K3: GRU scan (R8/R9 version, unchanged)
#define ACLOB \
  "a0","a1","a2","a3","a4","a5","a6","a7","a8","a9","a10","a11","a12","a13","a14","a15", \
  "a16","a17","a18","a19","a20","a21","a22","a23","a24","a25","a26","a27","a28","a29","a30","a31", \
  "a32","a33","a34","a35","a36","a37","a38","a39","a40","a41","a42","a43","a44","a45","a46","a47", \
  "a48","a49","a50","a51","a52","a53","a54","a55","a56","a57","a58","a59","a60","a61","a62","a63", \
  "a64","a65","a66","a67","a68","a69","a70","a71","a72","a73","a74","a75","a76","a77","a78","a79", \
  "a80","a81","a82","a83","a84","a85","a86","a87","a88","a89","a90","a91","a92","a93","a94","a95", \
  "a96","a97","a98","a99","a100","a101","a102","a103","a104","a105","a106","a107","a108","a109","a110","a111", \
  "a112","a113","a114","a115","a116","a117","a118","a119","a120","a121","a122","a123","a124","a125","a126","a127", \
  "a128","a129","a130","a131","a132","a133","a134","a135","a136","a137","a138","a139","a140","a141","a142","a143", \
  "a144","a145","a146","a147","a148","a149","a150","a151"

#define LF8(A0,A1, U, KT) do { \
  f32x2 _t = *(const f32x2*)(whh8 + (size_t)(((U) >> 1) * 256 + wid * 32 + ((U) & 1) * 16 + l16) * 256 + (KT) * 32 + quad * 8); \
  asm volatile("v_accvgpr_write_b32 a" #A0 ", %0\n\t" \
               "v_accvgpr_write_b32 a" #A1 ", %1" \
               :: "v"(_t[0]), "v"(_t[1]) : "a" #A0, "a" #A1); } while (0)

#define LFN(A0,A1,A2,A3, TC, KT) do { \
  f32x4 _t = *(const f32x4*)(whh16 + (size_t)(512 + wid * 32 + (TC) * 16 + l16) * 256 + (KT) * 32 + quad * 8); \
  asm volatile("v_accvgpr_write_b32 a" #A0 ", %0\n\t" \
               "v_accvgpr_write_b32 a" #A1 ", %1\n\t" \
               "v_accvgpr_write_b32 a" #A2 ", %2\n\t" \
               "v_accvgpr_write_b32 a" #A3 ", %3" \
               :: "v"(_t[0]), "v"(_t[1]), "v"(_t[2]), "v"(_t[3]) \
               : "a" #A0, "a" #A1, "a" #A2, "a" #A3); } while (0)

#define FP8G(P, F0,F1,F2,F3) \
  "v_mfma_f32_16x16x32_fp8_fp8 a[128:131], " P ", a[" F0 "], a[128:131]\n\t" \
  "v_mfma_f32_16x16x32_fp8_fp8 a[132:135], " P ", a[" F1 "], a[132:135]\n\t" \
  "v_mfma_f32_16x16x32_fp8_fp8 a[136:139], " P ", a[" F2 "], a[136:139]\n\t" \
  "v_mfma_f32_16x16x32_fp8_fp8 a[140:143], " P ", a[" F3 "], a[140:143]\n\t"

#define F16G(Q, G0,G1) \
  "v_mfma_f32_16x16x32_f16 a[144:147], " Q ", a[" G0 "], a[144:147]\n\t" \
  "v_mfma_f32_16x16x32_f16 a[148:151], " Q ", a[" G1 "], a[148:151]\n\t"

__global__ __launch_bounds__(512, 2) void gru_kernel(const f16* __restrict__ gi,
                                                     const f16* __restrict__ whh16,
                                                     const uint8_t* __restrict__ whh8,
                                                     const float* __restrict__ b_hh,
                                                     const float* __restrict__ W_out,
                                                     const float* __restrict__ b_out,
                                                     float* __restrict__ out) {
    __shared__ __align__(16) f16 hbufF[2][16 * 280];      // f16 h (n-gate A + head)
    __shared__ __align__(16) uint8_t hbuf8[2][16 * 272];  // fp8 h (rz A)
    const int tid = threadIdx.x, lane = tid & 63, wid = tid >> 6;   // wid 0..7
    const int quad = lane >> 4, l16 = lane & 15;
    const int bb = blockIdx.x;

    for (int i = tid; i < 16 * 280; i += 512) hbufF[1][i] = (f16)0.0f;
    for (int i = tid; i < 16 * 272; i += 512) hbuf8[1][i] = 0;

    LF8(0,1, 0,0);   LF8(2,3, 0,1);   LF8(4,5, 0,2);   LF8(6,7, 0,3);
    LF8(8,9, 0,4);   LF8(10,11, 0,5); LF8(12,13, 0,6); LF8(14,15, 0,7);
    LF8(16,17, 1,0); LF8(18,19, 1,1); LF8(20,21, 1,2); LF8(22,23, 1,3);
    LF8(24,25, 1,4); LF8(26,27, 1,5); LF8(28,29, 1,6); LF8(30,31, 1,7);
    LF8(32,33, 2,0); LF8(34,35, 2,1); LF8(36,37, 2,2); LF8(38,39, 2,3);
    LF8(40,41, 2,4); LF8(42,43, 2,5); LF8(44,45, 2,6); LF8(46,47, 2,7);
    LF8(48,49, 3,0); LF8(50,51, 3,1); LF8(52,53, 3,2); LF8(54,55, 3,3);
    LF8(56,57, 3,4); LF8(58,59, 3,5); LF8(60,61, 3,6); LF8(62,63, 3,7);
    LFN(64,65,66,67,   0,0); LFN(68,69,70,71,   0,1); LFN(72,73,74,75,   0,2); LFN(76,77,78,79,   0,3);
    LFN(80,81,82,83,   0,4); LFN(84,85,86,87,   0,5); LFN(88,89,90,91,   0,6); LFN(92,93,94,95,   0,7);
    LFN(96,97,98,99,   1,0); LFN(100,101,102,103, 1,1); LFN(104,105,106,107, 1,2); LFN(108,109,110,111, 1,3);
    LFN(112,113,114,115, 1,4); LFN(116,117,118,119, 1,5); LFN(120,121,122,123, 1,6); LFN(124,125,126,127, 1,7);

    float bhn[2];
#pragma unroll
    for (int tc = 0; tc < 2; tc++) bhn[tc] = b_hh[512 + wid * 32 + tc * 16 + l16];
    float hm[2][4];
#pragma unroll
    for (int tc = 0; tc < 2; tc++)
#pragma unroll
        for (int rr = 0; rr < 4; rr++) hm[tc][rr] = 0.f;

    uint32_t aF0 = (uint32_t)(uintptr_t)(__attribute__((address_space(3))) const void*)
                       (&hbufF[0][l16 * 280 + quad * 8]);
    uint32_t aF1 = (uint32_t)(uintptr_t)(__attribute__((address_space(3))) const void*)
                       (&hbufF[1][l16 * 280 + quad * 8]);
    uint32_t a80 = (uint32_t)(uintptr_t)(__attribute__((address_space(3))) const void*)
                       (&hbuf8[0][l16 * 272 + quad * 8]);
    uint32_t a81 = (uint32_t)(uintptr_t)(__attribute__((address_space(3))) const void*)
                       (&hbuf8[1][l16 * 272 + quad * 8]);

    const size_t lanebase = ((size_t)bb * 512 + tid) * 24;
    f16x4 gcur[6];
#pragma unroll
    for (int i = 0; i < 6; i++) gcur[i] = *(const f16x4*)(gi + lanebase + i * 4);

    const float zerof = 0.0f;
    BAR_LDS();

    for (int t = 0; t < 31; t++) {
        const uint32_t a8 = (t & 1) ? a80 : a81;
        const uint32_t aF = (t & 1) ? aF0 : aF1;
        float cc[24];
        f32x2 p0, p1, p2;
        f32x4 q0, q1, q2;
        asm volatile(
            // 6-deep pipeline: issue order == consumption order (p/q interleaved)
            "ds_read_b64  %[p0], %[a8] offset:0\n\t"
            "ds_read_b128 %[q0], %[aF] offset:0\n\t"
            "ds_read_b64  %[p1], %[a8] offset:32\n\t"
            "ds_read_b128 %[q1], %[aF] offset:64\n\t"
            "ds_read_b64  %[p2], %[a8] offset:64\n\t"
            "ds_read_b128 %[q2], %[aF] offset:128\n\t"
            "v_accvgpr_write_b32 a128, %[z]\n\tv_accvgpr_write_b32 a129, %[z]\n\t"
            "v_accvgpr_write_b32 a130, %[z]\n\tv_accvgpr_write_b32 a131, %[z]\n\t"
            "v_accvgpr_write_b32 a132, %[z]\n\tv_accvgpr_write_b32 a133, %[z]\n\t"
            "v_accvgpr_write_b32 a134, %[z]\n\tv_accvgpr_write_b32 a135, %[z]\n\t"
            "v_accvgpr_write_b32 a136, %[z]\n\tv_accvgpr_write_b32 a137, %[z]\n\t"
            "v_accvgpr_write_b32 a138, %[z]\n\tv_accvgpr_write_b32 a139, %[z]\n\t"
            "v_accvgpr_write_b32 a140, %[z]\n\tv_accvgpr_write_b32 a141, %[z]\n\t"
            "v_accvgpr_write_b32 a142, %[z]\n\tv_accvgpr_write_b32 a143, %[z]\n\t"
            "v_accvgpr_write_b32 a144, %[z]\n\tv_accvgpr_write_b32 a145, %[z]\n\t"
            "v_accvgpr_write_b32 a146, %[z]\n\tv_accvgpr_write_b32 a147, %[z]\n\t"
            "v_accvgpr_write_b32 a148, %[z]\n\tv_accvgpr_write_b32 a149, %[z]\n\t"
            "v_accvgpr_write_b32 a150, %[z]\n\tv_accvgpr_write_b32 a151, %[z]\n\t"
            "s_waitcnt lgkmcnt(5)\n\t"
            FP8G("%[p0]", "0:1","16:17","32:33","48:49")
            "ds_read_b64  %[p0], %[a8] offset:96\n\t"
            "s_waitcnt lgkmcnt(5)\n\t"
            F16G("%[q0]", "64:67","96:99")
            "ds_read_b128 %[q0], %[aF] offset:192\n\t"
            "s_waitcnt lgkmcnt(5)\n\t"
            FP8G("%[p1]", "2:3","18:19","34:35","50:51")
            "ds_read_b64  %[p1], %[a8] offset:128\n\t"
            "s_waitcnt lgkmcnt(5)\n\t"
            F16G("%[q1]", "68:71","100:103")
            "ds_read_b128 %[q1], %[aF] offset:256\n\t"
            "s_waitcnt lgkmcnt(5)\n\t"
            FP8G("%[p2]", "4:5","20:21","36:37","52:53")
            "ds_read_b64  %[p2], %[a8] offset:160\n\t"
            "s_waitcnt lgkmcnt(5)\n\t"
            F16G("%[q2]", "72:75","104:107")
            "ds_read_b128 %[q2], %[aF] offset:320\n\t"
            "s_waitcnt lgkmcnt(5)\n\t"
            FP8G("%[p0]", "6:7","22:23","38:39","54:55")
            "ds_read_b64  %[p0], %[a8] offset:192\n\t"
            "s_waitcnt lgkmcnt(5)\n\t"
            F16G("%[q0]", "76:79","108:111")
            "ds_read_b128 %[q0], %[aF] offset:384\n\t"
            "s_waitcnt lgkmcnt(5)\n\t"
            FP8G("%[p1]", "8:9","24:25","40:41","56:57")
            "ds_read_b64  %[p1], %[a8] offset:224\n\t"
            "s_waitcnt lgkmcnt(5)\n\t"
            F16G("%[q1]", "80:83","112:115")
            "ds_read_b128 %[q1], %[aF] offset:448\n\t"
            "s_waitcnt lgkmcnt(5)\n\t"
            FP8G("%[p2]", "10:11","26:27","42:43","58:59")
            "s_waitcnt lgkmcnt(4)\n\t"
            F16G("%[q2]", "84:87","116:119")
            "s_waitcnt lgkmcnt(3)\n\t"
            FP8G("%[p0]", "12:13","28:29","44:45","60:61")
            "s_waitcnt lgkmcnt(2)\n\t"
            F16G("%[q0]", "88:91","120:123")
            "s_waitcnt lgkmcnt(1)\n\t"
            FP8G("%[p1]", "14:15","30:31","46:47","62:63")
            "s_waitcnt lgkmcnt(0)\n\t"
            F16G("%[q1]", "92:95","124:127")
            "s_nop 7\n\ts_nop 7\n\ts_nop 7\n\ts_nop 7\n\t"
            "v_accvgpr_read_b32 %[c0], a128\n\tv_accvgpr_read_b32 %[c1], a129\n\t"
            "v_accvgpr_read_b32 %[c2], a130\n\tv_accvgpr_read_b32 %[c3], a131\n\t"
            "v_accvgpr_read_b32 %[c4], a132\n\tv_accvgpr_read_b32 %[c5], a133\n\t"
            "v_accvgpr_read_b32 %[c6], a134\n\tv_accvgpr_read_b32 %[c7], a135\n\t"
            "v_accvgpr_read_b32 %[c8], a136\n\tv_accvgpr_read_b32 %[c9], a137\n\t"
            "v_accvgpr_read_b32 %[c10], a138\n\tv_accvgpr_read_b32 %[c11], a139\n\t"
            "v_accvgpr_read_b32 %[c12], a140\n\tv_accvgpr_read_b32 %[c13], a141\n\t"
            "v_accvgpr_read_b32 %[c14], a142\n\tv_accvgpr_read_b32 %[c15], a143\n\t"
            "v_accvgpr_read_b32 %[c16], a144\n\tv_accvgpr_read_b32 %[c17], a145\n\t"
            "v_accvgpr_read_b32 %[c18], a146\n\tv_accvgpr_read_b32 %[c19], a147\n\t"
            "v_accvgpr_read_b32 %[c20], a148\n\tv_accvgpr_read_b32 %[c21], a149\n\t"
            "v_accvgpr_read_b32 %[c22], a150\n\tv_accvgpr_read_b32 %[c23], a151"
            : [c0]"=v"(cc[0]), [c1]"=v"(cc[1]), [c2]"=v"(cc[2]), [c3]"=v"(cc[3]),
              [c4]"=v"(cc[4]), [c5]"=v"(cc[5]), [c6]"=v"(cc[6]), [c7]"=v"(cc[7]),
              [c8]"=v"(cc[8]), [c9]"=v"(cc[9]), [c10]"=v"(cc[10]), [c11]"=v"(cc[11]),
              [c12]"=v"(cc[12]), [c13]"=v"(cc[13]), [c14]"=v"(cc[14]), [c15]"=v"(cc[15]),
              [c16]"=v"(cc[16]), [c17]"=v"(cc[17]), [c18]"=v"(cc[18]), [c19]"=v"(cc[19]),
              [c20]"=v"(cc[20]), [c21]"=v"(cc[21]), [c22]"=v"(cc[22]), [c23]"=v"(cc[23]),
              [p0]"=&v"(p0), [p1]"=&v"(p1), [p2]"=&v"(p2),
              [q0]"=&v"(q0), [q1]"=&v"(q1), [q2]"=&v"(q2)
            : [a8]"v"(a8), [aF]"v"(aF), [z]"v"(zerof)
            : ACLOB);

        // gate math: cc[(gs*2+tc)*4+rr] rz (x1/16), cc[16+tc*4+rr] n
        f16* hdF = hbufF[t & 1];
        uint8_t* hd8 = hbuf8[t & 1];
#pragma unroll
        for (int tc = 0; tc < 2; tc++) {
            const int hcx = wid * 32 + tc * 16 + l16;
#pragma unroll
            for (int rr = 0; rr < 4; rr++) {
                float rg = 1.f / (1.f + __expf(-fmaf(0.0625f, cc[tc * 4 + rr], (float)gcur[tc][rr])));
                float zg = 1.f / (1.f + __expf(-fmaf(0.0625f, cc[(2 + tc) * 4 + rr], (float)gcur[2 + tc][rr])));
                float ar = fmaf(rg, cc[16 + tc * 4 + rr] + bhn[tc], (float)gcur[4 + tc][rr]);
                float e2 = __expf(2.f * ar);
                float ng = 1.f - 2.f / (e2 + 1.f);            // tanh(ar)
                float h = fmaf(zg, hm[tc][rr] - ng, ng);      // (1-z)n + z*h
                hm[tc][rr] = h;
                hdF[(quad * 4 + rr) * 280 + hcx] = (f16)h;
                int pk = __builtin_amdgcn_cvt_pk_fp8_f32(h, h, 0, false);
                hd8[(quad * 4 + rr) * 272 + hcx] = (uint8_t)pk;
            }
        }
        // prefetch gi for t+1 (registers; survives lgkm-only barrier)
        {
            int tn = (t < 30) ? t + 1 : 30;
            const f16* gsrc = gi + (size_t)tn * 98304 + lanebase;
#pragma unroll
            for (int i = 0; i < 6; i++) gcur[i] = *(const f16x4*)(gsrc + i * 4);
        }
        BAR_LDS();
    }
    // output head: final h in hbufF[0]
    if (tid < 160) {
        int r = tid / 10, oc = tid - r * 10;
        const f16* hfin = hbufF[0];
        float s = b_out[oc];
        for (int k = 0; k < 256; k++) s += (float)hfin[r * 280 + k] * W_out[oc * 256 + k];
        out[(bb * 16 + r) * 10 + oc] = 1.f / (1.f + __expf(-s));
    }
}

// ---------------------------------------------------------------- launch
extern "C" void kernel_launch(void* const* d_in, const int* in_sizes, int n_in,
                              void* d_out, int out_size, void* d_ws, size_t ws_size,
                              hipStream_t stream) {
    const float* x     = (const float*)d_in[0];
    const float* W_aug = (const float*)d_in[1];
    // d_in[2] = b_aug — cancels in dx, unused
    const float* W_ih  = (const float*)d_in[3];
    const float* W_hh  = (const float*)d_in[4];
    const float* b_ih  = (const float*)d_in[5];
    const float* b_hh  = (const float*)d_in[6];
    const float* W_out = (const float*)d_in[7];
    const float* b_out = (const float*)d_in[8];
    float* out = (float*)d_out;

    char* ws = (char*)d_ws;
    const size_t SIG_BYTES  = (size_t)3968 * 2240 * 2;           // 17,776,640
    const size_t WIH_BYTES  = (size_t)768 * 2240 * 2;            //  3,440,640
    const size_t WHH_BYTES  = (size_t)768 * 256 * 2;             //    393,216
    const size_t WHH8_BYTES = (size_t)512 * 256;                 //    131,072
    const size_t GI_BYTES   = (size_t)31 * 8 * 512 * 24 * 2;     //  6,094,848
    if (ws_size < SIG_BYTES + WIH_BYTES + WHH_BYTES + WHH8_BYTES + GI_BYTES) return;
    f16* sig16    = (f16*)ws;
    f16* wih16    = (f16*)(ws + SIG_BYTES);
    f16* whh16    = (f16*)(ws + SIG_BYTES + WIH_BYTES);
    uint8_t* whh8 = (uint8_t*)(ws + SIG_BYTES + WIH_BYTES + WHH_BYTES);
    f16* giw      = (f16*)(ws + SIG_BYTES + WIH_BYTES + WHH_BYTES + WHH8_BYTES);

    hipLaunchKernelGGL(prep_kernel, dim3(2920), dim3(256), 0, stream,
                       x, W_aug, W_ih, W_hh, sig16, wih16, whh16, whh8);
    hipLaunchKernelGGL(gemm_kernel, dim3(6, 31), dim3(256), 0, stream,
                       sig16, wih16, b_ih, b_hh, giw);
    hipLaunchKernelGGL(gru_kernel, dim3(8), dim3(512), 0, stream,
                       giw, whh16, whh8, b_hh, W_out, b_out, out);
}

// Round 11
// 247.838 us; speedup vs baseline: 1.0167x; 1.0167x over previous
//
#include <hip/hip_runtime.h>
#include <hip/hip_bf16.h>
#include <stdint.h>

// Problem constants
// B=128 STREAM=512 IN_CH=4 EXTRA=5 GROUPS=2 DEPTH=3 STEP=16 LENGTH=32 RNN=256 OUT=10
// C=10 SIG_C=1110 W=31 F=2220, padded K = 2240, GEMM M = 31*128 = 3968, N = 768
// gi layout (f16): per (t, bb, tid) 24 contiguous f16:
//   off = ((t*8+bb)*512 + tid)*24 + (gs*2+tc)*4 + rr
// GRU: r,z gates fp8 e4m3 (W_hh*16) pinned a[0:63]; n gate f16 pinned a[64:127];
// acc a[128:151]; zero-quad a[152:155]. 6-deep ds_read pipeline (lgkmcnt(5)).
// GEMM: vmcnt(4) pipelined K-loop + XCD swizzle (t == lin mod 8 -> same-t blocks
// share one XCD's L2; A-tile fetched once per XCD instead of 6x).

typedef _Float16 f16;
typedef f16  f16x4 __attribute__((ext_vector_type(4)));
typedef f16  f16x8 __attribute__((ext_vector_type(8)));
typedef float f32x2 __attribute__((ext_vector_type(2)));
typedef float f32x4 __attribute__((ext_vector_type(4)));

#define ASYNC16(gp, lp) __builtin_amdgcn_global_load_lds( \
    (const __attribute__((address_space(1))) void*)(gp),  \
    (__attribute__((address_space(3))) void*)(lp), 16, 0, 0)

#define BAR_LDS() do { asm volatile("s_waitcnt lgkmcnt(0)" ::: "memory"); \
                       __builtin_amdgcn_s_barrier();                      \
                       asm volatile("" ::: "memory"); } while (0)

// ---------------------------------------------------------------- K0: prep
// blocks [0,840):    W_ih f32 -> f16 (pad 2220->2240), 8 elems/thread
// blocks [840,936):  W_hh f32 -> f16 (all) + fp8*16 (r,z rows), 8 elems/thread
// blocks [936,2920): signature chains, 4 per block
__global__ __launch_bounds__(256) void prep_kernel(const float* __restrict__ x,
                                                   const float* __restrict__ W_aug,
                                                   const float* __restrict__ Wih,
                                                   const float* __restrict__ Whh,
                                                   f16* __restrict__ sig16,
                                                   f16* __restrict__ wih16,
                                                   f16* __restrict__ whh16,
                                                   uint8_t* __restrict__ whh8) {
    __shared__ float dxs[4][31][10];
    const int tid = threadIdx.x;
    if (blockIdx.x < 840) {
        int c = blockIdx.x * 256 + tid;          // chunk 0..215039
        int r = c / 280, kc = (c - r * 280) * 8;
        const float* src = Wih + (size_t)r * 2220 + kc;
        f16x8 o;
        if (kc + 8 <= 2220) {
            float4 v0 = *(const float4*)(src);
            float4 v1 = *(const float4*)(src + 4);
            o[0]=(f16)v0.x; o[1]=(f16)v0.y; o[2]=(f16)v0.z; o[3]=(f16)v0.w;
            o[4]=(f16)v1.x; o[5]=(f16)v1.y; o[6]=(f16)v1.z; o[7]=(f16)v1.w;
        } else {
#pragma unroll
            for (int j = 0; j < 8; j++)
                o[j] = (f16)((kc + j < 2220) ? src[j] : 0.0f);
        }
        *(f16x8*)(wih16 + (size_t)r * 2240 + kc) = o;
        return;
    }
    if (blockIdx.x < 936) {
        int c2 = ((int)blockIdx.x - 840) * 256 + tid;    // 0..24575
        int j8 = c2 * 8;
        float w[8];
        {
            float4 v0 = *(const float4*)(Whh + j8);
            float4 v1 = *(const float4*)(Whh + j8 + 4);
            w[0]=v0.x; w[1]=v0.y; w[2]=v0.z; w[3]=v0.w;
            w[4]=v1.x; w[5]=v1.y; w[6]=v1.z; w[7]=v1.w;
        }
        f16x8 o;
#pragma unroll
        for (int j = 0; j < 8; j++) o[j] = (f16)w[j];
        *(f16x8*)(whh16 + j8) = o;
        if (j8 < 131072) {                       // r,z gate rows -> fp8 e4m3 (x16)
            uint32_t p01 = (uint32_t)__builtin_amdgcn_cvt_pk_fp8_f32(w[0]*16.f, w[1]*16.f, 0, false) & 0xffffu;
            uint32_t p23 = (uint32_t)__builtin_amdgcn_cvt_pk_fp8_f32(w[2]*16.f, w[3]*16.f, 0, false) & 0xffffu;
            uint32_t p45 = (uint32_t)__builtin_amdgcn_cvt_pk_fp8_f32(w[4]*16.f, w[5]*16.f, 0, false) & 0xffffu;
            uint32_t p67 = (uint32_t)__builtin_amdgcn_cvt_pk_fp8_f32(w[6]*16.f, w[7]*16.f, 0, false) & 0xffffu;
            uint2 st = make_uint2(p01 | (p23 << 16), p45 | (p67 << 16));
            *(uint2*)(whh8 + j8) = st;
        }
        return;
    }
    // ---- signature chains (block-uniform branch; __syncthreads safe)
    const int sub = tid >> 6, t64 = tid & 63;
    const int cid = ((int)blockIdx.x - 936) * 4 + sub;   // 0..7935
    const int w = cid % 31;
    const int bg = cid / 31;
    const int b = bg >> 1, g = bg & 1;
    if (t64 < 31) {
        int s = w * 16 + t64;
        const float4 x0 = *(const float4*)(x + ((size_t)b * 512 + s) * 4);
        const float4 x1 = *(const float4*)(x + ((size_t)b * 512 + s + 1) * 4);
        float d0 = x1.x - x0.x, d1 = x1.y - x0.y, d2 = x1.z - x0.z, d3 = x1.w - x0.w;
        dxs[sub][t64][0] = d0; dxs[sub][t64][1] = d1;
        dxs[sub][t64][2] = d2; dxs[sub][t64][3] = d3;
        dxs[sub][t64][4] = 1.0f / 511.0f;
#pragma unroll
        for (int e = 0; e < 5; e++) {
            const float* wa = W_aug + (g * 5 + e) * 4;
            dxs[sub][t64][5 + e] = d0 * wa[0] + d1 * wa[1] + d2 * wa[2] + d3 * wa[3];
        }
    }
    __syncthreads();
    size_t base = ((size_t)(w * 128 + b)) * 2240 + (size_t)g * 1110;
    if (t64 < 50) {
        int p0 = 2 * t64, p1 = p0 + 1;
        int i0 = p0 / 10, j0 = p0 % 10, j1 = j0 + 1;
        float s3a[10], s3b[10];
#pragma unroll
        for (int k = 0; k < 10; k++) { s3a[k] = 0.f; s3b[k] = 0.f; }
        float s2a = 0.f, s2b = 0.f, s1 = 0.f;
        for (int l = 0; l < 31; l++) {
            float dx[10];
#pragma unroll
            for (int c = 0; c < 10; c++) dx[c] = dxs[sub][l][c];
            float t0 = s1 + dx[i0] * (1.0f / 3.0f);
            float a0 = s2a + t0 * (0.5f * dx[j0]);
            float a1 = s2b + t0 * (0.5f * dx[j1]);
#pragma unroll
            for (int k = 0; k < 10; k++) { s3a[k] += a0 * dx[k]; s3b[k] += a1 * dx[k]; }
            float u = s1 + 0.5f * dx[i0];
            s2a += u * dx[j0];
            s2b += u * dx[j1];
            s1 += dx[i0];
        }
        sig16[base + 10 + p0] = (f16)s2a;
        sig16[base + 10 + p1] = (f16)s2b;
#pragma unroll
        for (int k = 0; k < 10; k++) {
            sig16[base + 110 + p0 * 10 + k] = (f16)s3a[k];
            sig16[base + 110 + p1 * 10 + k] = (f16)s3b[k];
        }
    } else if (t64 < 60) {
        int c = t64 - 50;
        float s = 0.f;
        for (int l = 0; l < 31; l++) s += dxs[sub][l][c];
        sig16[base + c] = (f16)s;
    }
    if (g == 1 && t64 < 20)
        sig16[((size_t)(w * 128 + b)) * 2240 + 2220 + t64] = (f16)0.0f;
}

// ---------------------------------------------------------------- K2: gi = sig @ W_ih.T + biases (f16, GRU lane order)
// 1D grid 192, XCD swizzle: t = (lin&7) + 8*(lin/48), n = (lin>>3)%6 -> same-t
// blocks have equal lin%8 (same XCD under round-robin) -> A-tile L2-shared.
__global__ __launch_bounds__(256) void gemm_kernel(const f16* __restrict__ A,     // 3968 x 2240
                                                   const f16* __restrict__ Bw,    // 768 x 2240 f16
                                                   const float* __restrict__ bias,
                                                   const float* __restrict__ bhh,
                                                   f16* __restrict__ Cgi) {
    const int lin = blockIdx.x;
    const int t = (lin & 7) + 8 * (lin / 48);
    const int nb = (lin >> 3) % 6;
    if (t >= 31) return;
    __shared__ __align__(16) f16 As[3][128 * 32];
    __shared__ __align__(16) f16 Bs[3][128 * 32];
    const int tid = threadIdx.x, lane = tid & 63, wid = tid >> 6;
    const int wm = wid >> 1, wn = wid & 1;
    const int Mbase = t * 128, Nbase = nb * 128;
    const int lr = lane >> 2, lk = lane & 3;
    const int l16 = lane & 15, quad = lane >> 4;
    const int r0a = wid * 32, r0b = wid * 32 + 16;
    const f16* gaA0 = A  + (size_t)(Mbase + r0a + lr) * 2240 + lk * 8;
    const f16* gaA1 = A  + (size_t)(Mbase + r0b + lr) * 2240 + lk * 8;
    const f16* gbB0 = Bw + (size_t)(Nbase + r0a + lr) * 2240 + lk * 8;
    const f16* gbB1 = Bw + (size_t)(Nbase + r0b + lr) * 2240 + lk * 8;

#define GISSUE(KT, BUF) do { \
        int _k0 = (KT) * 32; \
        ASYNC16(gaA0 + _k0, &As[BUF][r0a * 32]); \
        ASYNC16(gbB0 + _k0, &Bs[BUF][r0a * 32]); \
        ASYNC16(gaA1 + _k0, &As[BUF][r0b * 32]); \
        ASYNC16(gbB1 + _k0, &Bs[BUF][r0b * 32]); } while (0)

#define GCOMPUTE(BUF) do { \
        f16x8 af[4], bf[4]; \
        _Pragma("unroll") \
        for (int mt = 0; mt < 4; mt++) \
            af[mt] = *(const f16x8*)&As[BUF][(wm * 64 + mt * 16 + l16) * 32 + quad * 8]; \
        _Pragma("unroll") \
        for (int nt = 0; nt < 4; nt++) \
            bf[nt] = *(const f16x8*)&Bs[BUF][(wn * 64 + nt * 16 + l16) * 32 + quad * 8]; \
        _Pragma("unroll") \
        for (int mt = 0; mt < 4; mt++) \
            _Pragma("unroll") \
            for (int nt = 0; nt < 4; nt++) \
                acc[mt][nt] = __builtin_amdgcn_mfma_f32_16x16x32_f16(af[mt], bf[nt], acc[mt][nt], 0, 0, 0); } while (0)

    f32x4 acc[4][4];
#pragma unroll
    for (int mt = 0; mt < 4; mt++)
#pragma unroll
        for (int nt = 0; nt < 4; nt++) acc[mt][nt] = (f32x4){0.f, 0.f, 0.f, 0.f};

    GISSUE(0, 0);
    GISSUE(1, 1);
    for (int kt = 0; kt < 69; kt++) {
        // wait only the oldest 4 loads (tile kt); tile kt+1's 4 stay in flight
        asm volatile("s_waitcnt vmcnt(4) lgkmcnt(0)\n\ts_barrier" ::: "memory");
        if (kt < 68) GISSUE(kt + 2, (kt + 2) % 3);
        GCOMPUTE(kt % 3);
    }
    asm volatile("s_waitcnt vmcnt(0) lgkmcnt(0)\n\ts_barrier" ::: "memory");
    GCOMPUTE(0);   // tile 69 -> buffer 69%3 == 0

#pragma unroll
    for (int mt = 0; mt < 4; mt++) {
        const int bbv = wm * 4 + mt;
#pragma unroll
        for (int nt = 0; nt < 4; nt++) {
            int col = Nbase + wn * 64 + nt * 16 + l16;
            float bvv = bias[col] + (col < 512 ? bhh[col] : 0.0f);   // fold b_hh into r,z
            int gs = col >> 8, hcc = col & 255;
            int gw = hcc >> 5, gtc = (hcc >> 4) & 1, gl = hcc & 15;
            int gtid = gw * 64 + quad * 16 + gl;
            size_t off = ((size_t)(t * 8 + bbv) * 512 + gtid) * 24 + (gs * 2 + gtc) * 4;
            f16x4 st;
#pragma unroll
            for (int rr = 0; rr < 4; rr++) st[rr] = (f16)(acc[mt][nt][rr] + bvv);
            *(f16x4*)(Cgi + off) = st;
        }
    }
#undef GISSUE
#undef GCOMPUTE
}

// ---------------------------------------------------------------- K3: GRU scan
#define ACLOB \
  "a0","a1","a2","a3","a4","a5","a6","a7","a8","a9","a10","a11","a12","a13","a14","a15", \
  "a16","a17","a18","a19","a20","a21","a22","a23","a24","a25","a26","a27","a28","a29","a30","a31", \
  "a32","a33","a34","a35","a36","a37","a38","a39","a40","a41","a42","a43","a44","a45","a46","a47", \
  "a48","a49","a50","a51","a52","a53","a54","a55","a56","a57","a58","a59","a60","a61","a62","a63", \
  "a64","a65","a66","a67","a68","a69","a70","a71","a72","a73","a74","a75","a76","a77","a78","a79", \
  "a80","a81","a82","a83","a84","a85","a86","a87","a88","a89","a90","a91","a92","a93","a94","a95", \
  "a96","a97","a98","a99","a100","a101","a102","a103","a104","a105","a106","a107","a108","a109","a110","a111", \
  "a112","a113","a114","a115","a116","a117","a118","a119","a120","a121","a122","a123","a124","a125","a126","a127", \
  "a128","a129","a130","a131","a132","a133","a134","a135","a136","a137","a138","a139","a140","a141","a142","a143", \
  "a144","a145","a146","a147","a148","a149","a150","a151","a152","a153","a154","a155"

#define LF8(A0,A1, U, KT) do { \
  f32x2 _t = *(const f32x2*)(whh8 + (size_t)(((U) >> 1) * 256 + wid * 32 + ((U) & 1) * 16 + l16) * 256 + (KT) * 32 + quad * 8); \
  asm volatile("v_accvgpr_write_b32 a" #A0 ", %0\n\t" \
               "v_accvgpr_write_b32 a" #A1 ", %1" \
               :: "v"(_t[0]), "v"(_t[1]) : "a" #A0, "a" #A1); } while (0)

#define LFN(A0,A1,A2,A3, TC, KT) do { \
  f32x4 _t = *(const f32x4*)(whh16 + (size_t)(512 + wid * 32 + (TC) * 16 + l16) * 256 + (KT) * 32 + quad * 8); \
  asm volatile("v_accvgpr_write_b32 a" #A0 ", %0\n\t" \
               "v_accvgpr_write_b32 a" #A1 ", %1\n\t" \
               "v_accvgpr_write_b32 a" #A2 ", %2\n\t" \
               "v_accvgpr_write_b32 a" #A3 ", %3" \
               :: "v"(_t[0]), "v"(_t[1]), "v"(_t[2]), "v"(_t[3]) \
               : "a" #A0, "a" #A1, "a" #A2, "a" #A3); } while (0)

// accumulate variants (C = acc) and first-touch variants (C = zero-quad a[152:155])
#define FP8G(P, F0,F1,F2,F3) \
  "v_mfma_f32_16x16x32_fp8_fp8 a[128:131], " P ", a[" F0 "], a[128:131]\n\t" \
  "v_mfma_f32_16x16x32_fp8_fp8 a[132:135], " P ", a[" F1 "], a[132:135]\n\t" \
  "v_mfma_f32_16x16x32_fp8_fp8 a[136:139], " P ", a[" F2 "], a[136:139]\n\t" \
  "v_mfma_f32_16x16x32_fp8_fp8 a[140:143], " P ", a[" F3 "], a[140:143]\n\t"

#define FP8GZ(P, F0,F1,F2,F3) \
  "v_mfma_f32_16x16x32_fp8_fp8 a[128:131], " P ", a[" F0 "], a[152:155]\n\t" \
  "v_mfma_f32_16x16x32_fp8_fp8 a[132:135], " P ", a[" F1 "], a[152:155]\n\t" \
  "v_mfma_f32_16x16x32_fp8_fp8 a[136:139], " P ", a[" F2 "], a[152:155]\n\t" \
  "v_mfma_f32_16x16x32_fp8_fp8 a[140:143], " P ", a[" F3 "], a[152:155]\n\t"

#define F16G(Q, G0,G1) \
  "v_mfma_f32_16x16x32_f16 a[144:147], " Q ", a[" G0 "], a[144:147]\n\t" \
  "v_mfma_f32_16x16x32_f16 a[148:151], " Q ", a[" G1 "], a[148:151]\n\t"

#define F16GZ(Q, G0,G1) \
  "v_mfma_f32_16x16x32_f16 a[144:147], " Q ", a[" G0 "], a[152:155]\n\t" \
  "v_mfma_f32_16x16x32_f16 a[148:151], " Q ", a[" G1 "], a[152:155]\n\t"

__global__ __launch_bounds__(512, 2) void gru_kernel(const f16* __restrict__ gi,
                                                     const f16* __restrict__ whh16,
                                                     const uint8_t* __restrict__ whh8,
                                                     const float* __restrict__ b_hh,
                                                     const float* __restrict__ W_out,
                                                     const float* __restrict__ b_out,
                                                     float* __restrict__ out) {
    __shared__ __align__(16) f16 hbufF[2][16 * 280];      // f16 h (n-gate A + head)
    __shared__ __align__(16) uint8_t hbuf8[2][16 * 272];  // fp8 h (rz A)
    const int tid = threadIdx.x, lane = tid & 63, wid = tid >> 6;   // wid 0..7
    const int quad = lane >> 4, l16 = lane & 15;
    const int bb = blockIdx.x;

    for (int i = tid; i < 16 * 280; i += 512) hbufF[1][i] = (f16)0.0f;
    for (int i = tid; i < 16 * 272; i += 512) hbuf8[1][i] = 0;

    LF8(0,1, 0,0);   LF8(2,3, 0,1);   LF8(4,5, 0,2);   LF8(6,7, 0,3);
    LF8(8,9, 0,4);   LF8(10,11, 0,5); LF8(12,13, 0,6); LF8(14,15, 0,7);
    LF8(16,17, 1,0); LF8(18,19, 1,1); LF8(20,21, 1,2); LF8(22,23, 1,3);
    LF8(24,25, 1,4); LF8(26,27, 1,5); LF8(28,29, 1,6); LF8(30,31, 1,7);
    LF8(32,33, 2,0); LF8(34,35, 2,1); LF8(36,37, 2,2); LF8(38,39, 2,3);
    LF8(40,41, 2,4); LF8(42,43, 2,5); LF8(44,45, 2,6); LF8(46,47, 2,7);
    LF8(48,49, 3,0); LF8(50,51, 3,1); LF8(52,53, 3,2); LF8(54,55, 3,3);
    LF8(56,57, 3,4); LF8(58,59, 3,5); LF8(60,61, 3,6); LF8(62,63, 3,7);
    LFN(64,65,66,67,   0,0); LFN(68,69,70,71,   0,1); LFN(72,73,74,75,   0,2); LFN(76,77,78,79,   0,3);
    LFN(80,81,82,83,   0,4); LFN(84,85,86,87,   0,5); LFN(88,89,90,91,   0,6); LFN(92,93,94,95,   0,7);
    LFN(96,97,98,99,   1,0); LFN(100,101,102,103, 1,1); LFN(104,105,106,107, 1,2); LFN(108,109,110,111, 1,3);
    LFN(112,113,114,115, 1,4); LFN(116,117,118,119, 1,5); LFN(120,121,122,123, 1,6); LFN(124,125,126,127, 1,7);
    // zero-quad a[152:155] (persistent C operand for first MFMA of each chain)
    {
        const float z = 0.0f;
        asm volatile("v_accvgpr_write_b32 a152, %0\n\t"
                     "v_accvgpr_write_b32 a153, %0\n\t"
                     "v_accvgpr_write_b32 a154, %0\n\t"
                     "v_accvgpr_write_b32 a155, %0"
                     :: "v"(z) : "a152","a153","a154","a155");
    }

    float bhn[2];
#pragma unroll
    for (int tc = 0; tc < 2; tc++) bhn[tc] = b_hh[512 + wid * 32 + tc * 16 + l16];
    float hm[2][4];
#pragma unroll
    for (int tc = 0; tc < 2; tc++)
#pragma unroll
        for (int rr = 0; rr < 4; rr++) hm[tc][rr] = 0.f;

    uint32_t aF0 = (uint32_t)(uintptr_t)(__attribute__((address_space(3))) const void*)
                       (&hbufF[0][l16 * 280 + quad * 8]);
    uint32_t aF1 = (uint32_t)(uintptr_t)(__attribute__((address_space(3))) const void*)
                       (&hbufF[1][l16 * 280 + quad * 8]);
    uint32_t a80 = (uint32_t)(uintptr_t)(__attribute__((address_space(3))) const void*)
                       (&hbuf8[0][l16 * 272 + quad * 8]);
    uint32_t a81 = (uint32_t)(uintptr_t)(__attribute__((address_space(3))) const void*)
                       (&hbuf8[1][l16 * 272 + quad * 8]);

    const size_t lanebase = ((size_t)bb * 512 + tid) * 24;
    f16x4 gcur[6];
#pragma unroll
    for (int i = 0; i < 6; i++) gcur[i] = *(const f16x4*)(gi + lanebase + i * 4);

    BAR_LDS();

    for (int t = 0; t < 31; t++) {
        const uint32_t a8 = (t & 1) ? a80 : a81;
        const uint32_t aF = (t & 1) ? aF0 : aF1;
        float cc[24];
        f32x2 p0, p1, p2;
        f32x4 q0, q1, q2;
        asm volatile(
            // 6-deep pipeline: issue order == consumption order (p/q interleaved)
            "ds_read_b64  %[p0], %[a8] offset:0\n\t"
            "ds_read_b128 %[q0], %[aF] offset:0\n\t"
            "ds_read_b64  %[p1], %[a8] offset:32\n\t"
            "ds_read_b128 %[q1], %[aF] offset:64\n\t"
            "ds_read_b64  %[p2], %[a8] offset:64\n\t"
            "ds_read_b128 %[q2], %[aF] offset:128\n\t"
            "s_waitcnt lgkmcnt(5)\n\t"
            FP8GZ("%[p0]", "0:1","16:17","32:33","48:49")
            "ds_read_b64  %[p0], %[a8] offset:96\n\t"
            "s_waitcnt lgkmcnt(5)\n\t"
            F16GZ("%[q0]", "64:67","96:99")
            "ds_read_b128 %[q0], %[aF] offset:192\n\t"
            "s_waitcnt lgkmcnt(5)\n\t"
            FP8G("%[p1]", "2:3","18:19","34:35","50:51")
            "ds_read_b64  %[p1], %[a8] offset:128\n\t"
            "s_waitcnt lgkmcnt(5)\n\t"
            F16G("%[q1]", "68:71","100:103")
            "ds_read_b128 %[q1], %[aF] offset:256\n\t"
            "s_waitcnt lgkmcnt(5)\n\t"
            FP8G("%[p2]", "4:5","20:21","36:37","52:53")
            "ds_read_b64  %[p2], %[a8] offset:160\n\t"
            "s_waitcnt lgkmcnt(5)\n\t"
            F16G("%[q2]", "72:75","104:107")
            "ds_read_b128 %[q2], %[aF] offset:320\n\t"
            "s_waitcnt lgkmcnt(5)\n\t"
            FP8G("%[p0]", "6:7","22:23","38:39","54:55")
            "ds_read_b64  %[p0], %[a8] offset:192\n\t"
            "s_waitcnt lgkmcnt(5)\n\t"
            F16G("%[q0]", "76:79","108:111")
            "ds_read_b128 %[q0], %[aF] offset:384\n\t"
            "s_waitcnt lgkmcnt(5)\n\t"
            FP8G("%[p1]", "8:9","24:25","40:41","56:57")
            "ds_read_b64  %[p1], %[a8] offset:224\n\t"
            "s_waitcnt lgkmcnt(5)\n\t"
            F16G("%[q1]", "80:83","112:115")
            "ds_read_b128 %[q1], %[aF] offset:448\n\t"
            "s_waitcnt lgkmcnt(5)\n\t"
            FP8G("%[p2]", "10:11","26:27","42:43","58:59")
            "s_waitcnt lgkmcnt(4)\n\t"
            F16G("%[q2]", "84:87","116:119")
            "s_waitcnt lgkmcnt(3)\n\t"
            FP8G("%[p0]", "12:13","28:29","44:45","60:61")
            "s_waitcnt lgkmcnt(2)\n\t"
            F16G("%[q0]", "88:91","120:123")
            "s_waitcnt lgkmcnt(1)\n\t"
            FP8G("%[p1]", "14:15","30:31","46:47","62:63")
            "s_waitcnt lgkmcnt(0)\n\t"
            F16G("%[q1]", "92:95","124:127")
            "s_nop 7\n\ts_nop 7\n\ts_nop 7\n\ts_nop 7\n\t"
            "v_accvgpr_read_b32 %[c0], a128\n\tv_accvgpr_read_b32 %[c1], a129\n\t"
            "v_accvgpr_read_b32 %[c2], a130\n\tv_accvgpr_read_b32 %[c3], a131\n\t"
            "v_accvgpr_read_b32 %[c4], a132\n\tv_accvgpr_read_b32 %[c5], a133\n\t"
            "v_accvgpr_read_b32 %[c6], a134\n\tv_accvgpr_read_b32 %[c7], a135\n\t"
            "v_accvgpr_read_b32 %[c8], a136\n\tv_accvgpr_read_b32 %[c9], a137\n\t"
            "v_accvgpr_read_b32 %[c10], a138\n\tv_accvgpr_read_b32 %[c11], a139\n\t"
            "v_accvgpr_read_b32 %[c12], a140\n\tv_accvgpr_read_b32 %[c13], a141\n\t"
            "v_accvgpr_read_b32 %[c14], a142\n\tv_accvgpr_read_b32 %[c15], a143\n\t"
            "v_accvgpr_read_b32 %[c16], a144\n\tv_accvgpr_read_b32 %[c17], a145\n\t"
            "v_accvgpr_read_b32 %[c18], a146\n\tv_accvgpr_read_b32 %[c19], a147\n\t"
            "v_accvgpr_read_b32 %[c20], a148\n\tv_accvgpr_read_b32 %[c21], a149\n\t"
            "v_accvgpr_read_b32 %[c22], a150\n\tv_accvgpr_read_b32 %[c23], a151"
            : [c0]"=v"(cc[0]), [c1]"=v"(cc[1]), [c2]"=v"(cc[2]), [c3]"=v"(cc[3]),
              [c4]"=v"(cc[4]), [c5]"=v"(cc[5]), [c6]"=v"(cc[6]), [c7]"=v"(cc[7]),
              [c8]"=v"(cc[8]), [c9]"=v"(cc[9]), [c10]"=v"(cc[10]), [c11]"=v"(cc[11]),
              [c12]"=v"(cc[12]), [c13]"=v"(cc[13]), [c14]"=v"(cc[14]), [c15]"=v"(cc[15]),
              [c16]"=v"(cc[16]), [c17]"=v"(cc[17]), [c18]"=v"(cc[18]), [c19]"=v"(cc[19]),
              [c20]"=v"(cc[20]), [c21]"=v"(cc[21]), [c22]"=v"(cc[22]), [c23]"=v"(cc[23]),
              [p0]"=&v"(p0), [p1]"=&v"(p1), [p2]"=&v"(p2),
              [q0]"=&v"(q0), [q1]"=&v"(q1), [q2]"=&v"(q2)
            : [a8]"v"(a8), [aF]"v"(aF)
            : ACLOB);

        // gate math: cc[(gs*2+tc)*4+rr] rz (x1/16), cc[16+tc*4+rr] n
        f16* hdF = hbufF[t & 1];
        uint8_t* hd8 = hbuf8[t & 1];
#pragma unroll
        for (int tc = 0; tc < 2; tc++) {
            const int hcx = wid * 32 + tc * 16 + l16;
#pragma unroll
            for (int rr = 0; rr < 4; rr++) {
                float rg = 1.f / (1.f + __expf(-fmaf(0.0625f, cc[tc * 4 + rr], (float)gcur[tc][rr])));
                float zg = 1.f / (1.f + __expf(-fmaf(0.0625f, cc[(2 + tc) * 4 + rr], (float)gcur[2 + tc][rr])));
                float ar = fmaf(rg, cc[16 + tc * 4 + rr] + bhn[tc], (float)gcur[4 + tc][rr]);
                float e2 = __expf(2.f * ar);
                float ng = 1.f - 2.f / (e2 + 1.f);            // tanh(ar)
                float h = fmaf(zg, hm[tc][rr] - ng, ng);      // (1-z)n + z*h
                hm[tc][rr] = h;
                hdF[(quad * 4 + rr) * 280 + hcx] = (f16)h;
                int pk = __builtin_amdgcn_cvt_pk_fp8_f32(h, h, 0, false);
                hd8[(quad * 4 + rr) * 272 + hcx] = (uint8_t)pk;
            }
        }
        // prefetch gi for t+1 (registers; survives lgkm-only barrier)
        {
            int tn = (t < 30) ? t + 1 : 30;
            const f16* gsrc = gi + (size_t)tn * 98304 + lanebase;
#pragma unroll
            for (int i = 0; i < 6; i++) gcur[i] = *(const f16x4*)(gsrc + i * 4);
        }
        BAR_LDS();
    }
    // output head: final h in hbufF[0]
    if (tid < 160) {
        int r = tid / 10, oc = tid - r * 10;
        const f16* hfin = hbufF[0];
        float s = b_out[oc];
        for (int k = 0; k < 256; k++) s += (float)hfin[r * 280 + k] * W_out[oc * 256 + k];
        out[(bb * 16 + r) * 10 + oc] = 1.f / (1.f + __expf(-s));
    }
}

// ---------------------------------------------------------------- launch
extern "C" void kernel_launch(void* const* d_in, const int* in_sizes, int n_in,
                              void* d_out, int out_size, void* d_ws, size_t ws_size,
                              hipStream_t stream) {
    const float* x     = (const float*)d_in[0];
    const float* W_aug = (const float*)d_in[1];
    // d_in[2] = b_aug — cancels in dx, unused
    const float* W_ih  = (const float*)d_in[3];
    const float* W_hh  = (const float*)d_in[4];
    const float* b_ih  = (const float*)d_in[5];
    const float* b_hh  = (const float*)d_in[6];
    const float* W_out = (const float*)d_in[7];
    const float* b_out = (const float*)d_in[8];
    float* out = (float*)d_out;

    char* ws = (char*)d_ws;
    const size_t SIG_BYTES  = (size_t)3968 * 2240 * 2;           // 17,776,640
    const size_t WIH_BYTES  = (size_t)768 * 2240 * 2;            //  3,440,640
    const size_t WHH_BYTES  = (size_t)768 * 256 * 2;             //    393,216
    const size_t WHH8_BYTES = (size_t)512 * 256;                 //    131,072
    const size_t GI_BYTES   = (size_t)31 * 8 * 512 * 24 * 2;     //  6,094,848
    if (ws_size < SIG_BYTES + WIH_BYTES + WHH_BYTES + WHH8_BYTES + GI_BYTES) return;
    f16* sig16    = (f16*)ws;
    f16* wih16    = (f16*)(ws + SIG_BYTES);
    f16* whh16    = (f16*)(ws + SIG_BYTES + WIH_BYTES);
    uint8_t* whh8 = (uint8_t*)(ws + SIG_BYTES + WIH_BYTES + WHH_BYTES);
    f16* giw      = (f16*)(ws + SIG_BYTES + WIH_BYTES + WHH_BYTES + WHH8_BYTES);

    hipLaunchKernelGGL(prep_kernel, dim3(2920), dim3(256), 0, stream,
                       x, W_aug, W_ih, W_hh, sig16, wih16, whh16, whh8);
    hipLaunchKernelGGL(gemm_kernel, dim3(192), dim3(256), 0, stream,
                       sig16, wih16, b_ih, b_hh, giw);
    hipLaunchKernelGGL(gru_kernel, dim3(8), dim3(512), 0, stream,
                       giw, whh16, whh8, b_hh, W_out, b_out, out);
}

// Round 12
// 242.247 us; speedup vs baseline: 1.0402x; 1.0231x over previous
//
#include <hip/hip_runtime.h>
#include <hip/hip_bf16.h>
#include <stdint.h>

// Problem constants
// B=128 STREAM=512 IN_CH=4 EXTRA=5 GROUPS=2 DEPTH=3 STEP=16 LENGTH=32 RNN=256 OUT=10
// C=10 SIG_C=1110 W=31 F=2220, padded K = 2240, GEMM M = 31*128 = 3968, N = 768
// gi layout (f16, COALESCED): chunk u of thread gtid at step (t,bb):
//   f16 offset = ((t*8+bb)*6 + u)*2048 + gtid*4,  u = gs*2+gtc in [0,6)
//   -> GEMM epilogue writes consecutive 8B per lane; GRU reads 6 coalesced f16x4.
// GRU: r,z gates fp8 e4m3 (W_hh*16) pinned a[0:63]; n gate f16 pinned a[64:127];
// acc a[128:151]; zero-quad a[152:155]. 6-deep ds_read pipeline (lgkmcnt(5)).

typedef _Float16 f16;
typedef f16  f16x4 __attribute__((ext_vector_type(4)));
typedef f16  f16x8 __attribute__((ext_vector_type(8)));
typedef float f32x2 __attribute__((ext_vector_type(2)));
typedef float f32x4 __attribute__((ext_vector_type(4)));

#define ASYNC16(gp, lp) __builtin_amdgcn_global_load_lds( \
    (const __attribute__((address_space(1))) void*)(gp),  \
    (__attribute__((address_space(3))) void*)(lp), 16, 0, 0)

#define BAR_LDS() do { asm volatile("s_waitcnt lgkmcnt(0)" ::: "memory"); \
                       __builtin_amdgcn_s_barrier();                      \
                       asm volatile("" ::: "memory"); } while (0)

// ---------------------------------------------------------------- K0: prep
// blocks [0,840):    W_ih f32 -> f16 (pad 2220->2240), 8 elems/thread
// blocks [840,936):  W_hh f32 -> f16 (all) + fp8*16 (r,z rows), 8 elems/thread
// blocks [936,2920): signature chains, 4 per block (register-resident inner loop)
__global__ __launch_bounds__(256) void prep_kernel(const float* __restrict__ x,
                                                   const float* __restrict__ W_aug,
                                                   const float* __restrict__ Wih,
                                                   const float* __restrict__ Whh,
                                                   f16* __restrict__ sig16,
                                                   f16* __restrict__ wih16,
                                                   f16* __restrict__ whh16,
                                                   uint8_t* __restrict__ whh8) {
    __shared__ float dxs[4][31][10];
    const int tid = threadIdx.x;
    if (blockIdx.x < 840) {
        int c = blockIdx.x * 256 + tid;          // chunk 0..215039
        int r = c / 280, kc = (c - r * 280) * 8;
        const float* src = Wih + (size_t)r * 2220 + kc;
        f16x8 o;
        if (kc + 8 <= 2220) {
            float4 v0 = *(const float4*)(src);
            float4 v1 = *(const float4*)(src + 4);
            o[0]=(f16)v0.x; o[1]=(f16)v0.y; o[2]=(f16)v0.z; o[3]=(f16)v0.w;
            o[4]=(f16)v1.x; o[5]=(f16)v1.y; o[6]=(f16)v1.z; o[7]=(f16)v1.w;
        } else {
#pragma unroll
            for (int j = 0; j < 8; j++)
                o[j] = (f16)((kc + j < 2220) ? src[j] : 0.0f);
        }
        *(f16x8*)(wih16 + (size_t)r * 2240 + kc) = o;
        return;
    }
    if (blockIdx.x < 936) {
        int c2 = ((int)blockIdx.x - 840) * 256 + tid;    // 0..24575
        int j8 = c2 * 8;
        float w[8];
        {
            float4 v0 = *(const float4*)(Whh + j8);
            float4 v1 = *(const float4*)(Whh + j8 + 4);
            w[0]=v0.x; w[1]=v0.y; w[2]=v0.z; w[3]=v0.w;
            w[4]=v1.x; w[5]=v1.y; w[6]=v1.z; w[7]=v1.w;
        }
        f16x8 o;
#pragma unroll
        for (int j = 0; j < 8; j++) o[j] = (f16)w[j];
        *(f16x8*)(whh16 + j8) = o;
        if (j8 < 131072) {                       // r,z gate rows -> fp8 e4m3 (x16)
            uint32_t p01 = (uint32_t)__builtin_amdgcn_cvt_pk_fp8_f32(w[0]*16.f, w[1]*16.f, 0, false) & 0xffffu;
            uint32_t p23 = (uint32_t)__builtin_amdgcn_cvt_pk_fp8_f32(w[2]*16.f, w[3]*16.f, 0, false) & 0xffffu;
            uint32_t p45 = (uint32_t)__builtin_amdgcn_cvt_pk_fp8_f32(w[4]*16.f, w[5]*16.f, 0, false) & 0xffffu;
            uint32_t p67 = (uint32_t)__builtin_amdgcn_cvt_pk_fp8_f32(w[6]*16.f, w[7]*16.f, 0, false) & 0xffffu;
            uint2 st = make_uint2(p01 | (p23 << 16), p45 | (p67 << 16));
            *(uint2*)(whh8 + j8) = st;
        }
        return;
    }
    // ---- signature chains (block-uniform branch; __syncthreads safe)
    const int sub = tid >> 6, t64 = tid & 63;
    const int cid = ((int)blockIdx.x - 936) * 4 + sub;   // 0..7935
    const int w = cid % 31;
    const int bg = cid / 31;
    const int b = bg >> 1, g = bg & 1;
    if (t64 < 31) {
        int s = w * 16 + t64;
        const float4 x0 = *(const float4*)(x + ((size_t)b * 512 + s) * 4);
        const float4 x1 = *(const float4*)(x + ((size_t)b * 512 + s + 1) * 4);
        float d0 = x1.x - x0.x, d1 = x1.y - x0.y, d2 = x1.z - x0.z, d3 = x1.w - x0.w;
        dxs[sub][t64][0] = d0; dxs[sub][t64][1] = d1;
        dxs[sub][t64][2] = d2; dxs[sub][t64][3] = d3;
        dxs[sub][t64][4] = 1.0f / 511.0f;
#pragma unroll
        for (int e = 0; e < 5; e++) {
            const float* wa = W_aug + (g * 5 + e) * 4;
            dxs[sub][t64][5 + e] = d0 * wa[0] + d1 * wa[1] + d2 * wa[2] + d3 * wa[3];
        }
    }
    __syncthreads();
    size_t base = ((size_t)(w * 128 + b)) * 2240 + (size_t)g * 1110;
    if (t64 < 50) {
        int p0 = 2 * t64, p1 = p0 + 1;
        int i0 = p0 / 10, j0 = p0 % 10, j1 = j0 + 1;   // p0 even -> j1 <= 9
        // loop-invariant LDS pointers: dynamic column index resolved ONCE
        const float* dz  = &dxs[sub][0][0];
        const float* pI  = dz + i0;
        const float* pJ0 = dz + j0;
        const float* pJ1 = dz + j1;
        float s3a[10], s3b[10];                        // constant-indexed -> registers
#pragma unroll
        for (int k = 0; k < 10; k++) { s3a[k] = 0.f; s3b[k] = 0.f; }
        float s2a = 0.f, s2b = 0.f, s1 = 0.f;
        for (int l = 0; l < 31; l++) {
            const float* row = dz + l * 10;
            float di  = pI[l * 10];
            float dj0 = pJ0[l * 10];
            float dj1 = pJ1[l * 10];
            float t0 = s1 + di * (1.0f / 3.0f);
            float a0 = s2a + t0 * (0.5f * dj0);
            float a1 = s2b + t0 * (0.5f * dj1);
#pragma unroll
            for (int k = 0; k < 10; k++) {
                float dk = row[k];
                s3a[k] += a0 * dk;
                s3b[k] += a1 * dk;
            }
            float u = s1 + 0.5f * di;
            s2a += u * dj0;
            s2b += u * dj1;
            s1 += di;
        }
        sig16[base + 10 + p0] = (f16)s2a;
        sig16[base + 10 + p1] = (f16)s2b;
#pragma unroll
        for (int k = 0; k < 10; k++) {
            sig16[base + 110 + p0 * 10 + k] = (f16)s3a[k];
            sig16[base + 110 + p1 * 10 + k] = (f16)s3b[k];
        }
    } else if (t64 < 60) {
        int c = t64 - 50;
        const float* pc = &dxs[sub][0][0] + c;
        float s = 0.f;
        for (int l = 0; l < 31; l++) s += pc[l * 10];
        sig16[base + c] = (f16)s;
    }
    if (g == 1 && t64 < 20)
        sig16[((size_t)(w * 128 + b)) * 2240 + 2220 + t64] = (f16)0.0f;
}

// ---------------------------------------------------------------- K2: gi = sig @ W_ih.T + biases (f16, coalesced GRU layout)
// 1D grid 192, XCD swizzle: t = (lin&7) + 8*(lin/48), n = (lin>>3)%6.
__global__ __launch_bounds__(256) void gemm_kernel(const f16* __restrict__ A,     // 3968 x 2240
                                                   const f16* __restrict__ Bw,    // 768 x 2240 f16
                                                   const float* __restrict__ bias,
                                                   const float* __restrict__ bhh,
                                                   f16* __restrict__ Cgi) {
    const int lin = blockIdx.x;
    const int t = (lin & 7) + 8 * (lin / 48);
    const int nb = (lin >> 3) % 6;
    if (t >= 31) return;
    __shared__ __align__(16) f16 As[3][128 * 32];
    __shared__ __align__(16) f16 Bs[3][128 * 32];
    const int tid = threadIdx.x, lane = tid & 63, wid = tid >> 6;
    const int wm = wid >> 1, wn = wid & 1;
    const int Mbase = t * 128, Nbase = nb * 128;
    const int lr = lane >> 2, lk = lane & 3;
    const int l16 = lane & 15, quad = lane >> 4;
    const int r0a = wid * 32, r0b = wid * 32 + 16;
    const f16* gaA0 = A  + (size_t)(Mbase + r0a + lr) * 2240 + lk * 8;
    const f16* gaA1 = A  + (size_t)(Mbase + r0b + lr) * 2240 + lk * 8;
    const f16* gbB0 = Bw + (size_t)(Nbase + r0a + lr) * 2240 + lk * 8;
    const f16* gbB1 = Bw + (size_t)(Nbase + r0b + lr) * 2240 + lk * 8;

#define GISSUE(KT, BUF) do { \
        int _k0 = (KT) * 32; \
        ASYNC16(gaA0 + _k0, &As[BUF][r0a * 32]); \
        ASYNC16(gbB0 + _k0, &Bs[BUF][r0a * 32]); \
        ASYNC16(gaA1 + _k0, &As[BUF][r0b * 32]); \
        ASYNC16(gbB1 + _k0, &Bs[BUF][r0b * 32]); } while (0)

#define GCOMPUTE(BUF) do { \
        f16x8 af[4], bf[4]; \
        _Pragma("unroll") \
        for (int mt = 0; mt < 4; mt++) \
            af[mt] = *(const f16x8*)&As[BUF][(wm * 64 + mt * 16 + l16) * 32 + quad * 8]; \
        _Pragma("unroll") \
        for (int nt = 0; nt < 4; nt++) \
            bf[nt] = *(const f16x8*)&Bs[BUF][(wn * 64 + nt * 16 + l16) * 32 + quad * 8]; \
        _Pragma("unroll") \
        for (int mt = 0; mt < 4; mt++) \
            _Pragma("unroll") \
            for (int nt = 0; nt < 4; nt++) \
                acc[mt][nt] = __builtin_amdgcn_mfma_f32_16x16x32_f16(af[mt], bf[nt], acc[mt][nt], 0, 0, 0); } while (0)

    f32x4 acc[4][4];
#pragma unroll
    for (int mt = 0; mt < 4; mt++)
#pragma unroll
        for (int nt = 0; nt < 4; nt++) acc[mt][nt] = (f32x4){0.f, 0.f, 0.f, 0.f};

    GISSUE(0, 0);
    GISSUE(1, 1);
    for (int kt = 0; kt < 69; kt++) {
        // wait only the oldest 4 loads (tile kt); tile kt+1's 4 stay in flight
        asm volatile("s_waitcnt vmcnt(4) lgkmcnt(0)\n\ts_barrier" ::: "memory");
        if (kt < 68) GISSUE(kt + 2, (kt + 2) % 3);
        GCOMPUTE(kt % 3);
    }
    asm volatile("s_waitcnt vmcnt(0) lgkmcnt(0)\n\ts_barrier" ::: "memory");
    GCOMPUTE(0);   // tile 69 -> buffer 69%3 == 0

    // epilogue: coalesced chunk layout -- consecutive lanes write consecutive 8B
#pragma unroll
    for (int mt = 0; mt < 4; mt++) {
        const int bbv = wm * 4 + mt;
#pragma unroll
        for (int nt = 0; nt < 4; nt++) {
            int col = Nbase + wn * 64 + nt * 16 + l16;
            float bvv = bias[col] + (col < 512 ? bhh[col] : 0.0f);   // fold b_hh into r,z
            int gs = col >> 8, hcc = col & 255;
            int gw = hcc >> 5, gtc = (hcc >> 4) & 1, gl = hcc & 15;
            int u = gs * 2 + gtc;
            int gtid = gw * 64 + quad * 16 + gl;
            size_t off = ((size_t)((t * 8 + bbv) * 6 + u)) * 2048 + (size_t)gtid * 4;
            f16x4 st;
#pragma unroll
            for (int rr = 0; rr < 4; rr++) st[rr] = (f16)(acc[mt][nt][rr] + bvv);
            *(f16x4*)(Cgi + off) = st;
        }
    }
#undef GISSUE
#undef GCOMPUTE
}

// ---------------------------------------------------------------- K3: GRU scan
#define ACLOB \
  "a0","a1","a2","a3","a4","a5","a6","a7","a8","a9","a10","a11","a12","a13","a14","a15", \
  "a16","a17","a18","a19","a20","a21","a22","a23","a24","a25","a26","a27","a28","a29","a30","a31", \
  "a32","a33","a34","a35","a36","a37","a38","a39","a40","a41","a42","a43","a44","a45","a46","a47", \
  "a48","a49","a50","a51","a52","a53","a54","a55","a56","a57","a58","a59","a60","a61","a62","a63", \
  "a64","a65","a66","a67","a68","a69","a70","a71","a72","a73","a74","a75","a76","a77","a78","a79", \
  "a80","a81","a82","a83","a84","a85","a86","a87","a88","a89","a90","a91","a92","a93","a94","a95", \
  "a96","a97","a98","a99","a100","a101","a102","a103","a104","a105","a106","a107","a108","a109","a110","a111", \
  "a112","a113","a114","a115","a116","a117","a118","a119","a120","a121","a122","a123","a124","a125","a126","a127", \
  "a128","a129","a130","a131","a132","a133","a134","a135","a136","a137","a138","a139","a140","a141","a142","a143", \
  "a144","a145","a146","a147","a148","a149","a150","a151","a152","a153","a154","a155"

#define LF8(A0,A1, U, KT) do { \
  f32x2 _t = *(const f32x2*)(whh8 + (size_t)(((U) >> 1) * 256 + wid * 32 + ((U) & 1) * 16 + l16) * 256 + (KT) * 32 + quad * 8); \
  asm volatile("v_accvgpr_write_b32 a" #A0 ", %0\n\t" \
               "v_accvgpr_write_b32 a" #A1 ", %1" \
               :: "v"(_t[0]), "v"(_t[1]) : "a" #A0, "a" #A1); } while (0)

#define LFN(A0,A1,A2,A3, TC, KT) do { \
  f32x4 _t = *(const f32x4*)(whh16 + (size_t)(512 + wid * 32 + (TC) * 16 + l16) * 256 + (KT) * 32 + quad * 8); \
  asm volatile("v_accvgpr_write_b32 a" #A0 ", %0\n\t" \
               "v_accvgpr_write_b32 a" #A1 ", %1\n\t" \
               "v_accvgpr_write_b32 a" #A2 ", %2\n\t" \
               "v_accvgpr_write_b32 a" #A3 ", %3" \
               :: "v"(_t[0]), "v"(_t[1]), "v"(_t[2]), "v"(_t[3]) \
               : "a" #A0, "a" #A1, "a" #A2, "a" #A3); } while (0)

#define FP8G(P, F0,F1,F2,F3) \
  "v_mfma_f32_16x16x32_fp8_fp8 a[128:131], " P ", a[" F0 "], a[128:131]\n\t" \
  "v_mfma_f32_16x16x32_fp8_fp8 a[132:135], " P ", a[" F1 "], a[132:135]\n\t" \
  "v_mfma_f32_16x16x32_fp8_fp8 a[136:139], " P ", a[" F2 "], a[136:139]\n\t" \
  "v_mfma_f32_16x16x32_fp8_fp8 a[140:143], " P ", a[" F3 "], a[140:143]\n\t"

#define FP8GZ(P, F0,F1,F2,F3) \
  "v_mfma_f32_16x16x32_fp8_fp8 a[128:131], " P ", a[" F0 "], a[152:155]\n\t" \
  "v_mfma_f32_16x16x32_fp8_fp8 a[132:135], " P ", a[" F1 "], a[152:155]\n\t" \
  "v_mfma_f32_16x16x32_fp8_fp8 a[136:139], " P ", a[" F2 "], a[152:155]\n\t" \
  "v_mfma_f32_16x16x32_fp8_fp8 a[140:143], " P ", a[" F3 "], a[152:155]\n\t"

#define F16G(Q, G0,G1) \
  "v_mfma_f32_16x16x32_f16 a[144:147], " Q ", a[" G0 "], a[144:147]\n\t" \
  "v_mfma_f32_16x16x32_f16 a[148:151], " Q ", a[" G1 "], a[148:151]\n\t"

#define F16GZ(Q, G0,G1) \
  "v_mfma_f32_16x16x32_f16 a[144:147], " Q ", a[" G0 "], a[152:155]\n\t" \
  "v_mfma_f32_16x16x32_f16 a[148:151], " Q ", a[" G1 "], a[152:155]\n\t"

__global__ __launch_bounds__(512, 2) void gru_kernel(const f16* __restrict__ gi,
                                                     const f16* __restrict__ whh16,
                                                     const uint8_t* __restrict__ whh8,
                                                     const float* __restrict__ b_hh,
                                                     const float* __restrict__ W_out,
                                                     const float* __restrict__ b_out,
                                                     float* __restrict__ out) {
    __shared__ __align__(16) f16 hbufF[2][16 * 280];      // f16 h (n-gate A + head)
    __shared__ __align__(16) uint8_t hbuf8[2][16 * 272];  // fp8 h (rz A)
    const int tid = threadIdx.x, lane = tid & 63, wid = tid >> 6;   // wid 0..7
    const int quad = lane >> 4, l16 = lane & 15;
    const int bb = blockIdx.x;

    for (int i = tid; i < 16 * 280; i += 512) hbufF[1][i] = (f16)0.0f;
    for (int i = tid; i < 16 * 272; i += 512) hbuf8[1][i] = 0;

    LF8(0,1, 0,0);   LF8(2,3, 0,1);   LF8(4,5, 0,2);   LF8(6,7, 0,3);
    LF8(8,9, 0,4);   LF8(10,11, 0,5); LF8(12,13, 0,6); LF8(14,15, 0,7);
    LF8(16,17, 1,0); LF8(18,19, 1,1); LF8(20,21, 1,2); LF8(22,23, 1,3);
    LF8(24,25, 1,4); LF8(26,27, 1,5); LF8(28,29, 1,6); LF8(30,31, 1,7);
    LF8(32,33, 2,0); LF8(34,35, 2,1); LF8(36,37, 2,2); LF8(38,39, 2,3);
    LF8(40,41, 2,4); LF8(42,43, 2,5); LF8(44,45, 2,6); LF8(46,47, 2,7);
    LF8(48,49, 3,0); LF8(50,51, 3,1); LF8(52,53, 3,2); LF8(54,55, 3,3);
    LF8(56,57, 3,4); LF8(58,59, 3,5); LF8(60,61, 3,6); LF8(62,63, 3,7);
    LFN(64,65,66,67,   0,0); LFN(68,69,70,71,   0,1); LFN(72,73,74,75,   0,2); LFN(76,77,78,79,   0,3);
    LFN(80,81,82,83,   0,4); LFN(84,85,86,87,   0,5); LFN(88,89,90,91,   0,6); LFN(92,93,94,95,   0,7);
    LFN(96,97,98,99,   1,0); LFN(100,101,102,103, 1,1); LFN(104,105,106,107, 1,2); LFN(108,109,110,111, 1,3);
    LFN(112,113,114,115, 1,4); LFN(116,117,118,119, 1,5); LFN(120,121,122,123, 1,6); LFN(124,125,126,127, 1,7);
    // zero-quad a[152:155] (persistent C operand for first MFMA of each chain)
    {
        const float z = 0.0f;
        asm volatile("v_accvgpr_write_b32 a152, %0\n\t"
                     "v_accvgpr_write_b32 a153, %0\n\t"
                     "v_accvgpr_write_b32 a154, %0\n\t"
                     "v_accvgpr_write_b32 a155, %0"
                     :: "v"(z) : "a152","a153","a154","a155");
    }

    float bhn[2];
#pragma unroll
    for (int tc = 0; tc < 2; tc++) bhn[tc] = b_hh[512 + wid * 32 + tc * 16 + l16];
    float hm[2][4];
#pragma unroll
    for (int tc = 0; tc < 2; tc++)
#pragma unroll
        for (int rr = 0; rr < 4; rr++) hm[tc][rr] = 0.f;

    uint32_t aF0 = (uint32_t)(uintptr_t)(__attribute__((address_space(3))) const void*)
                       (&hbufF[0][l16 * 280 + quad * 8]);
    uint32_t aF1 = (uint32_t)(uintptr_t)(__attribute__((address_space(3))) const void*)
                       (&hbufF[1][l16 * 280 + quad * 8]);
    uint32_t a80 = (uint32_t)(uintptr_t)(__attribute__((address_space(3))) const void*)
                       (&hbuf8[0][l16 * 272 + quad * 8]);
    uint32_t a81 = (uint32_t)(uintptr_t)(__attribute__((address_space(3))) const void*)
                       (&hbuf8[1][l16 * 272 + quad * 8]);

    // coalesced gi: per (t,bb) slab = 12288 f16; chunk u at u*2048; thread at tid*4
    const size_t lanebase = (size_t)bb * 12288 + (size_t)tid * 4;
    f16x4 gcur[6];
#pragma unroll
    for (int u = 0; u < 6; u++)
        gcur[u] = *(const f16x4*)(gi + lanebase + u * 2048);

    BAR_LDS();

    for (int t = 0; t < 31; t++) {
        const uint32_t a8 = (t & 1) ? a80 : a81;
        const uint32_t aF = (t & 1) ? aF0 : aF1;
        float cc[24];
        f32x2 p0, p1, p2;
        f32x4 q0, q1, q2;
        asm volatile(
            // 6-deep pipeline: issue order == consumption order (p/q interleaved)
            "ds_read_b64  %[p0], %[a8] offset:0\n\t"
            "ds_read_b128 %[q0], %[aF] offset:0\n\t"
            "ds_read_b64  %[p1], %[a8] offset:32\n\t"
            "ds_read_b128 %[q1], %[aF] offset:64\n\t"
            "ds_read_b64  %[p2], %[a8] offset:64\n\t"
            "ds_read_b128 %[q2], %[aF] offset:128\n\t"
            "s_waitcnt lgkmcnt(5)\n\t"
            FP8GZ("%[p0]", "0:1","16:17","32:33","48:49")
            "ds_read_b64  %[p0], %[a8] offset:96\n\t"
            "s_waitcnt lgkmcnt(5)\n\t"
            F16GZ("%[q0]", "64:67","96:99")
            "ds_read_b128 %[q0], %[aF] offset:192\n\t"
            "s_waitcnt lgkmcnt(5)\n\t"
            FP8G("%[p1]", "2:3","18:19","34:35","50:51")
            "ds_read_b64  %[p1], %[a8] offset:128\n\t"
            "s_waitcnt lgkmcnt(5)\n\t"
            F16G("%[q1]", "68:71","100:103")
            "ds_read_b128 %[q1], %[aF] offset:256\n\t"
            "s_waitcnt lgkmcnt(5)\n\t"
            FP8G("%[p2]", "4:5","20:21","36:37","52:53")
            "ds_read_b64  %[p2], %[a8] offset:160\n\t"
            "s_waitcnt lgkmcnt(5)\n\t"
            F16G("%[q2]", "72:75","104:107")
            "ds_read_b128 %[q2], %[aF] offset:320\n\t"
            "s_waitcnt lgkmcnt(5)\n\t"
            FP8G("%[p0]", "6:7","22:23","38:39","54:55")
            "ds_read_b64  %[p0], %[a8] offset:192\n\t"
            "s_waitcnt lgkmcnt(5)\n\t"
            F16G("%[q0]", "76:79","108:111")
            "ds_read_b128 %[q0], %[aF] offset:384\n\t"
            "s_waitcnt lgkmcnt(5)\n\t"
            FP8G("%[p1]", "8:9","24:25","40:41","56:57")
            "ds_read_b64  %[p1], %[a8] offset:224\n\t"
            "s_waitcnt lgkmcnt(5)\n\t"
            F16G("%[q1]", "80:83","112:115")
            "ds_read_b128 %[q1], %[aF] offset:448\n\t"
            "s_waitcnt lgkmcnt(5)\n\t"
            FP8G("%[p2]", "10:11","26:27","42:43","58:59")
            "s_waitcnt lgkmcnt(4)\n\t"
            F16G("%[q2]", "84:87","116:119")
            "s_waitcnt lgkmcnt(3)\n\t"
            FP8G("%[p0]", "12:13","28:29","44:45","60:61")
            "s_waitcnt lgkmcnt(2)\n\t"
            F16G("%[q0]", "88:91","120:123")
            "s_waitcnt lgkmcnt(1)\n\t"
            FP8G("%[p1]", "14:15","30:31","46:47","62:63")
            "s_waitcnt lgkmcnt(0)\n\t"
            F16G("%[q1]", "92:95","124:127")
            "s_nop 7\n\ts_nop 7\n\ts_nop 7\n\ts_nop 7\n\t"
            "v_accvgpr_read_b32 %[c0], a128\n\tv_accvgpr_read_b32 %[c1], a129\n\t"
            "v_accvgpr_read_b32 %[c2], a130\n\tv_accvgpr_read_b32 %[c3], a131\n\t"
            "v_accvgpr_read_b32 %[c4], a132\n\tv_accvgpr_read_b32 %[c5], a133\n\t"
            "v_accvgpr_read_b32 %[c6], a134\n\tv_accvgpr_read_b32 %[c7], a135\n\t"
            "v_accvgpr_read_b32 %[c8], a136\n\tv_accvgpr_read_b32 %[c9], a137\n\t"
            "v_accvgpr_read_b32 %[c10], a138\n\tv_accvgpr_read_b32 %[c11], a139\n\t"
            "v_accvgpr_read_b32 %[c12], a140\n\tv_accvgpr_read_b32 %[c13], a141\n\t"
            "v_accvgpr_read_b32 %[c14], a142\n\tv_accvgpr_read_b32 %[c15], a143\n\t"
            "v_accvgpr_read_b32 %[c16], a144\n\tv_accvgpr_read_b32 %[c17], a145\n\t"
            "v_accvgpr_read_b32 %[c18], a146\n\tv_accvgpr_read_b32 %[c19], a147\n\t"
            "v_accvgpr_read_b32 %[c20], a148\n\tv_accvgpr_read_b32 %[c21], a149\n\t"
            "v_accvgpr_read_b32 %[c22], a150\n\tv_accvgpr_read_b32 %[c23], a151"
            : [c0]"=v"(cc[0]), [c1]"=v"(cc[1]), [c2]"=v"(cc[2]), [c3]"=v"(cc[3]),
              [c4]"=v"(cc[4]), [c5]"=v"(cc[5]), [c6]"=v"(cc[6]), [c7]"=v"(cc[7]),
              [c8]"=v"(cc[8]), [c9]"=v"(cc[9]), [c10]"=v"(cc[10]), [c11]"=v"(cc[11]),
              [c12]"=v"(cc[12]), [c13]"=v"(cc[13]), [c14]"=v"(cc[14]), [c15]"=v"(cc[15]),
              [c16]"=v"(cc[16]), [c17]"=v"(cc[17]), [c18]"=v"(cc[18]), [c19]"=v"(cc[19]),
              [c20]"=v"(cc[20]), [c21]"=v"(cc[21]), [c22]"=v"(cc[22]), [c23]"=v"(cc[23]),
              [p0]"=&v"(p0), [p1]"=&v"(p1), [p2]"=&v"(p2),
              [q0]"=&v"(q0), [q1]"=&v"(q1), [q2]"=&v"(q2)
            : [a8]"v"(a8), [aF]"v"(aF)
            : ACLOB);

        // gate math: cc[(gs*2+tc)*4+rr] rz (x1/16), cc[16+tc*4+rr] n
        f16* hdF = hbufF[t & 1];
        uint8_t* hd8 = hbuf8[t & 1];
#pragma unroll
        for (int tc = 0; tc < 2; tc++) {
            const int hcx = wid * 32 + tc * 16 + l16;
#pragma unroll
            for (int rr = 0; rr < 4; rr++) {
                float rg = 1.f / (1.f + __expf(-fmaf(0.0625f, cc[tc * 4 + rr], (float)gcur[tc][rr])));
                float zg = 1.f / (1.f + __expf(-fmaf(0.0625f, cc[(2 + tc) * 4 + rr], (float)gcur[2 + tc][rr])));
                float ar = fmaf(rg, cc[16 + tc * 4 + rr] + bhn[tc], (float)gcur[4 + tc][rr]);
                float e2 = __expf(2.f * ar);
                float ng = 1.f - 2.f / (e2 + 1.f);            // tanh(ar)
                float h = fmaf(zg, hm[tc][rr] - ng, ng);      // (1-z)n + z*h
                hm[tc][rr] = h;
                hdF[(quad * 4 + rr) * 280 + hcx] = (f16)h;
                int pk = __builtin_amdgcn_cvt_pk_fp8_f32(h, h, 0, false);
                hd8[(quad * 4 + rr) * 272 + hcx] = (uint8_t)pk;
            }
        }
        // prefetch gi for t+1 (registers; survives lgkm-only barrier)
        {
            int tn = (t < 30) ? t + 1 : 30;
            const f16* gsrc = gi + (size_t)tn * 98304 + lanebase;
#pragma unroll
            for (int u = 0; u < 6; u++)
                gcur[u] = *(const f16x4*)(gsrc + u * 2048);
        }
        BAR_LDS();
    }
    // output head: final h in hbufF[0]
    if (tid < 160) {
        int r = tid / 10, oc = tid - r * 10;
        const f16* hfin = hbufF[0];
        float s = b_out[oc];
        for (int k = 0; k < 256; k++) s += (float)hfin[r * 280 + k] * W_out[oc * 256 + k];
        out[(bb * 16 + r) * 10 + oc] = 1.f / (1.f + __expf(-s));
    }
}

// ---------------------------------------------------------------- launch
extern "C" void kernel_launch(void* const* d_in, const int* in_sizes, int n_in,
                              void* d_out, int out_size, void* d_ws, size_t ws_size,
                              hipStream_t stream) {
    const float* x     = (const float*)d_in[0];
    const float* W_aug = (const float*)d_in[1];
    // d_in[2] = b_aug — cancels in dx, unused
    const float* W_ih  = (const float*)d_in[3];
    const float* W_hh  = (const float*)d_in[4];
    const float* b_ih  = (const float*)d_in[5];
    const float* b_hh  = (const float*)d_in[6];
    const float* W_out = (const float*)d_in[7];
    const float* b_out = (const float*)d_in[8];
    float* out = (float*)d_out;

    char* ws = (char*)d_ws;
    const size_t SIG_BYTES  = (size_t)3968 * 2240 * 2;           // 17,776,640
    const size_t WIH_BYTES  = (size_t)768 * 2240 * 2;            //  3,440,640
    const size_t WHH_BYTES  = (size_t)768 * 256 * 2;             //    393,216
    const size_t WHH8_BYTES = (size_t)512 * 256;                 //    131,072
    const size_t GI_BYTES   = (size_t)31 * 8 * 6 * 512 * 4 * 2;  //  6,094,848
    if (ws_size < SIG_BYTES + WIH_BYTES + WHH_BYTES + WHH8_BYTES + GI_BYTES) return;
    f16* sig16    = (f16*)ws;
    f16* wih16    = (f16*)(ws + SIG_BYTES);
    f16* whh16    = (f16*)(ws + SIG_BYTES + WIH_BYTES);
    uint8_t* whh8 = (uint8_t*)(ws + SIG_BYTES + WIH_BYTES + WHH_BYTES);
    f16* giw      = (f16*)(ws + SIG_BYTES + WIH_BYTES + WHH_BYTES + WHH8_BYTES);

    hipLaunchKernelGGL(prep_kernel, dim3(2920), dim3(256), 0, stream,
                       x, W_aug, W_ih, W_hh, sig16, wih16, whh16, whh8);
    hipLaunchKernelGGL(gemm_kernel, dim3(192), dim3(256), 0, stream,
                       sig16, wih16, b_ih, b_hh, giw);
    hipLaunchKernelGGL(gru_kernel, dim3(8), dim3(512), 0, stream,
                       giw, whh16, whh8, b_hh, W_out, b_out, out);
}